// Round 2
// baseline (15046.727 us; speedup 1.0000x reference)
//
#include <hip/hip_runtime.h>

// Problem: B=4, H=8, S=2048, D=64
// out  = [B*H*S*D]  floats   (first 4,194,304 of d_out)
// p    = [B*H*S*S]  floats   (next 134,217,728 of d_out)
#define NB 4
#define NH 8
#define NS 2048
#define ND 64
#define NBH (NB * NH)

typedef float f32x4 __attribute__((ext_vector_type(4)));

constexpr int TQ = 128;   // q rows per block
constexpr int TK = 128;   // k cols per tile
constexpr int NT = NS / TK;
constexpr size_t PM_BYTES = (size_t)NB * NS * (NS / 8);   // 2 MiB packed mask

// k-loop barrier: LDS-ordering only. Deliberately does NOT drain vmcnt, so
// p zero-fill stores and prefetch loads float freely across tiles.
__device__ __forceinline__ void barrier_lds() {
    __builtin_amdgcn_sched_barrier(0);
    asm volatile("s_waitcnt lgkmcnt(0)" ::: "memory");
    __builtin_amdgcn_s_barrier();
    __builtin_amdgcn_sched_barrier(0);
}

// ---------------------------------------------------------------------------
// Pack mask int32 -> 1 bit/key. pm[(b*NS + q)*256 + g] bit i = mask[b][q][g*8+i].
// Fully coalesced both sides. 67 MB read + 2 MB write ~= 12 us.
// ---------------------------------------------------------------------------
__global__ __launch_bounds__(256)
void pack_mask_kernel(const int* __restrict__ mask, unsigned char* __restrict__ pm)
{
    int idx = blockIdx.x * 256 + threadIdx.x;          // (b*NS + q)*256 + g
    const int* mp = mask + (size_t)idx * 8;
    int4 a = *(const int4*)mp;
    int4 b = *(const int4*)(mp + 4);
    unsigned int v = (a.x != 0)        | ((a.y != 0) << 1)
                   | ((a.z != 0) << 2) | ((a.w != 0) << 3)
                   | ((b.x != 0) << 4) | ((b.y != 0) << 5)
                   | ((b.z != 0) << 6) | ((b.w != 0) << 7);
    pm[idx] = (unsigned char)v;
}

// ---------------------------------------------------------------------------
// Kernel 1: fp32 QK^T with per-row masked top-2 logit tracking.
// Same numerics as round 1 (bit-identical accumulation + top-2 logic).
// New: raw LDS-only barriers, K-tile register prefetch, packed-mask prefetch,
// nontemporal zero-fill stores.
// ---------------------------------------------------------------------------
template<bool PACKED>
__global__ __launch_bounds__(256, 2)
void qk_argmax_kernel(const float* __restrict__ Q,
                      const float* __restrict__ K,
                      const float* __restrict__ V,
                      const int*   __restrict__ mask,
                      const unsigned char* __restrict__ pm,
                      float* __restrict__ outp,
                      float* __restrict__ p,
                      int* __restrict__ wsl, int wscap)
{
    __shared__ float qs[TQ * ND];   // f4 idx = row*16 + (c4 ^ (row>>3))
    __shared__ float ks[TK * ND];
    __shared__ int   argb[TQ];

    const int t  = threadIdx.x;
    const int tx = t & 15;          // key group (8 keys each)
    const int ty = t >> 4;          // row group (8 rows each), 0..15
    const int bh = blockIdx.y;      // 0..31
    const int b  = bh >> 3;
    const int q0 = blockIdx.x * TQ;

    const float* Qb = Q + ((size_t)bh * NS + q0) * ND;
    const float* Kb = K + (size_t)bh * NS * ND;
    const float* Vb = V + (size_t)bh * NS * ND;
    const int*   mb = mask + (size_t)b * NS * NS + (size_t)q0 * NS;
    const unsigned char* pmb = PACKED ? pm + ((size_t)b * NS + q0) * 256 : nullptr;
    float*       pb = p + ((size_t)bh * NS + q0) * NS;

    f32x4* qs4 = (f32x4*)qs;
    f32x4* ks4 = (f32x4*)ks;

    f32x4 kpref[8];                 // next K tile (register prefetch)
    unsigned char mpre[8];          // packed mask bytes, one per row (PACKED)
    int4 m0[8], m1[8];              // fallback mask prefetch (!PACKED)

    auto prefetch_masks = [&](int kt_) {
        if constexpr (PACKED) {
            const unsigned char* pr = pmb + kt_ * 16 + tx;
            #pragma unroll
            for (int j = 0; j < 8; ++j) mpre[j] = pr[(size_t)(ty * 8 + j) * 256];
        } else {
            const int* mrow = mb + kt_ * TK + tx * 8;
            #pragma unroll
            for (int j = 0; j < 8; ++j) {
                m0[j] = *(const int4*)(mrow + (size_t)(ty * 8 + j) * NS);
                m1[j] = *(const int4*)(mrow + (size_t)(ty * 8 + j) * NS + 4);
            }
        }
    };
    auto load_kpref = [&](int kt_) {
        #pragma unroll
        for (int s = 0; s < 8; ++s) {
            int f = t + 256 * s; int row = f >> 4, c4 = f & 15;
            kpref[s] = *(const f32x4*)(Kb + (size_t)(kt_ * TK + row) * ND + c4 * 4);
        }
    };
    auto write_ks = [&]() {
        #pragma unroll
        for (int s = 0; s < 8; ++s) {
            int f = t + 256 * s; int row = f >> 4, c4 = f & 15;
            ks4[row * 16 + (c4 ^ (row >> 3))] = kpref[s];
        }
    };

    // ---- prologue: stage Q + K tile 0, prefetch K tile 1 + masks(0) ----
    {
        f32x4 qpre[8], kpre0[8];
        #pragma unroll
        for (int s = 0; s < 8; ++s) {
            int f = t + 256 * s; int row = f >> 4, c4 = f & 15;
            qpre[s] = *(const f32x4*)(Qb + row * ND + c4 * 4);
        }
        #pragma unroll
        for (int s = 0; s < 8; ++s) {
            int f = t + 256 * s; int row = f >> 4, c4 = f & 15;
            kpre0[s] = *(const f32x4*)(Kb + (size_t)row * ND + c4 * 4);
        }
        load_kpref(1);
        prefetch_masks(0);
        #pragma unroll
        for (int s = 0; s < 8; ++s) {
            int f = t + 256 * s; int row = f >> 4, c4 = f & 15;
            qs4[row * 16 + (c4 ^ (row >> 3))] = qpre[s];
            ks4[row * 16 + (c4 ^ (row >> 3))] = kpre0[s];
        }
    }
    barrier_lds();

    float rm1[8], rm2[8];
    int   ri1[8];
    #pragma unroll
    for (int j = 0; j < 8; ++j) { rm1[j] = -1e30f; rm2[j] = -1e30f; ri1[j] = 0; }

    for (int kt = 0; kt < NT; ++kt) {
        // ---- compute 128x128 logit tile (identical numerics to round 1) ----
        float acc[8][8];
        #pragma unroll
        for (int j = 0; j < 8; ++j)
            #pragma unroll
            for (int i = 0; i < 8; ++i) acc[j][i] = 0.f;

        #pragma unroll 2
        for (int dd = 0; dd < 16; ++dd) {
            f32x4 qv[8], kv[8];
            #pragma unroll
            for (int j = 0; j < 8; ++j) qv[j] = qs4[(ty * 8 + j) * 16 + (dd ^ ty)];
            #pragma unroll
            for (int i = 0; i < 8; ++i) kv[i] = ks4[(tx * 8 + i) * 16 + (dd ^ tx)];
            #pragma unroll
            for (int j = 0; j < 8; ++j)
                #pragma unroll
                for (int i = 0; i < 8; ++i) {
                    acc[j][i] += qv[j].x * kv[i].x;
                    acc[j][i] += qv[j].y * kv[i].y;
                    acc[j][i] += qv[j].z * kv[i].z;
                    acc[j][i] += qv[j].w * kv[i].w;
                }
        }

        // ---- epilogue: mask, top-2, nontemporal zero-fill ----
        float* pz = pb + (size_t)(ty * 8) * NS + kt * TK + tx * 4;
        #pragma unroll
        for (int j = 0; j < 8; ++j) {
            float l[8];
            if constexpr (PACKED) {
                unsigned int mb_ = mpre[j];
                #pragma unroll
                for (int i = 0; i < 8; ++i)
                    l[i] = (mb_ & (1u << i)) ? acc[j][i] : -1e30f;
            } else {
                l[0] = m0[j].x ? acc[j][0] : -1e30f;
                l[1] = m0[j].y ? acc[j][1] : -1e30f;
                l[2] = m0[j].z ? acc[j][2] : -1e30f;
                l[3] = m0[j].w ? acc[j][3] : -1e30f;
                l[4] = m1[j].x ? acc[j][4] : -1e30f;
                l[5] = m1[j].y ? acc[j][5] : -1e30f;
                l[6] = m1[j].z ? acc[j][6] : -1e30f;
                l[7] = m1[j].w ? acc[j][7] : -1e30f;
            }

            float a1 = l[0]; int ai = 0; float a2 = -1e30f;
            #pragma unroll
            for (int i = 1; i < 8; ++i) {
                if (l[i] > a1) { a2 = a1; a1 = l[i]; ai = i; }
                else           { a2 = fmaxf(a2, l[i]); }
            }
            int gkey = kt * TK + tx * 8 + ai;
            if (a1 > rm1[j]) { rm2[j] = fmaxf(rm1[j], a2); rm1[j] = a1; ri1[j] = gkey; }
            else             { rm2[j] = fmaxf(rm2[j], fmaxf(a1, -1e30f)); }

            f32x4 z = {0.f, 0.f, 0.f, 0.f};
            __builtin_nontemporal_store(z, (f32x4*)(pz + (size_t)j * NS));
            __builtin_nontemporal_store(z, (f32x4*)(pz + (size_t)j * NS + 64));
        }

        // ---- stage next K tile; barriers order LDS only (stores float) ----
        if (kt < NT - 1) {
            barrier_lds();                 // all waves done reading ks[kt]
            write_ks();                    // kpref(kt+1) -> LDS
            prefetch_masks(kt + 1);
            if (kt + 2 < NT) load_kpref(kt + 2);
            barrier_lds();                 // ks[kt+1] visible
        }
    }

    // ---- reduce top-2 across the 16 tx lanes (unchanged from round 1) ----
    #pragma unroll
    for (int j = 0; j < 8; ++j) {
        float m1 = rm1[j], m2 = rm2[j];
        int   i1 = ri1[j];
        #pragma unroll
        for (int d = 1; d < 16; d <<= 1) {
            float om1 = __shfl_xor(m1, d, 64);
            float om2 = __shfl_xor(m2, d, 64);
            int   oi1 = __shfl_xor(i1, d, 64);
            float nm1; int ni1; float nm2;
            if (om1 > m1)      { nm1 = om1; ni1 = oi1; nm2 = fmaxf(om2, m1); }
            else if (om1 < m1) { nm1 = m1;  ni1 = i1;  nm2 = fmaxf(m2, om1); }
            else {
                nm1 = m1; ni1 = i1;
                nm2 = (oi1 == i1) ? fmaxf(m2, om2) : m1; // distinct-key tie -> gap 0
            }
            m1 = nm1; i1 = ni1; m2 = nm2;
        }
        if (tx == 0) {
            int qrow = ty * 8 + j;
            float s1 = __expf(m1) * 0.125f;
            bool clean = (m1 > -1e29f) && (s1 < 1e38f) && (m1 - m2 > 15.0f);
            if (clean) argb[qrow] = i1;
            else if (wscap > 0) {
                argb[qrow] = -1;
                int idx = atomicAdd(wsl, 1);
                if (idx < wscap) wsl[1 + idx] = bh * NS + q0 + qrow;
            } else {
                argb[qrow] = i1;   // no workspace: best-effort fallback
            }
        }
    }
    __syncthreads();   // FULL drain (vmcnt(0)): zero stores complete before 1.0

    // ---- emit one-hot + out = V[argmax] for clean rows ----
    #pragma unroll
    for (int s = 0; s < 8; ++s) {
        int task = t + 256 * s;          // 2048 tasks = 128 rows x 16 float4s
        int row = task >> 4, c4 = task & 15;
        int a = argb[row];
        if (a >= 0) {
            *(float4*)(outp + ((size_t)bh * NS + q0 + row) * ND + c4 * 4) =
                *(const float4*)(Vb + (size_t)a * ND + c4 * 4);
            if (c4 == 0) pb[(size_t)row * NS + a] = 1.0f;
        }
    }
}

// ---------------------------------------------------------------------------
// Kernel 2: exact reference softmax for listed (non-one-hot) rows (unchanged).
// ---------------------------------------------------------------------------
__global__ __launch_bounds__(256)
void slow_rows_kernel(const float* __restrict__ Q, const float* __restrict__ K,
                      const float* __restrict__ V, const int* __restrict__ mask,
                      float* __restrict__ outp, float* __restrict__ p,
                      const int* __restrict__ wsl, int wscap)
{
    __shared__ float qr[ND];
    __shared__ float redm[4], redz[4];
    __shared__ float ol[ND];
    int n = wsl[0];
    if (n > wscap) n = wscap;
    const int t = threadIdx.x;
    const int lane = t & 63, w = t >> 6;

    for (int ii = blockIdx.x; ii < n; ii += gridDim.x) {
        int row = wsl[1 + ii];           // global row = bh*NS + q
        int bh = row >> 11, q = row & (NS - 1), b = bh >> 3;
        const float* Qr = Q + (size_t)row * ND;
        const float* Kb = K + (size_t)bh * NS * ND;
        const float* Vb = V + (size_t)bh * NS * ND;
        const int*   mr = mask + (size_t)b * NS * NS + (size_t)q * NS;

        __syncthreads();
        if (t < 16) ((float4*)qr)[t] = ((const float4*)Qr)[t];
        if (t < ND) ol[t] = 0.f;
        __syncthreads();

        float sc[8];
        int k0 = t * 8;
        #pragma unroll
        for (int i = 0; i < 8; ++i) {
            const float* kr = Kb + (size_t)(k0 + i) * ND;
            float a = 0.f;
            for (int d = 0; d < ND; d += 4) {
                float4 kv = *(const float4*)(kr + d);
                a += qr[d] * kv.x; a += qr[d + 1] * kv.y;
                a += qr[d + 2] * kv.z; a += qr[d + 3] * kv.w;
            }
            sc[i] = mr[k0 + i] ? __expf(a) * 0.125f : -1e9f;
        }
        float m = sc[0];
        #pragma unroll
        for (int i = 1; i < 8; ++i) m = fmaxf(m, sc[i]);
        #pragma unroll
        for (int d = 1; d < 64; d <<= 1) m = fmaxf(m, __shfl_xor(m, d, 64));
        if (lane == 0) redm[w] = m;
        __syncthreads();
        m = fmaxf(fmaxf(redm[0], redm[1]), fmaxf(redm[2], redm[3]));

        float e[8]; float z = 0.f;
        #pragma unroll
        for (int i = 0; i < 8; ++i) { e[i] = __expf(sc[i] - m); z += e[i]; }
        #pragma unroll
        for (int d = 1; d < 64; d <<= 1) z += __shfl_xor(z, d, 64);
        if (lane == 0) redz[w] = z;
        __syncthreads();
        float Z = redz[0] + redz[1] + redz[2] + redz[3];
        float inv = 1.f / Z;

        float* pr = p + (size_t)row * NS + k0;
        float4 o0, o1;
        o0.x = e[0] * inv; o0.y = e[1] * inv; o0.z = e[2] * inv; o0.w = e[3] * inv;
        o1.x = e[4] * inv; o1.y = e[5] * inv; o1.z = e[6] * inv; o1.w = e[7] * inv;
        *(float4*)pr = o0; *(float4*)(pr + 4) = o1;

        #pragma unroll
        for (int i = 0; i < 8; ++i) {
            float pv = e[i] * inv;
            if (pv > 0.f) {
                const float* vr = Vb + (size_t)(k0 + i) * ND;
                for (int d = 0; d < ND; ++d) atomicAdd(&ol[d], pv * vr[d]);
            }
        }
        __syncthreads();
        if (t < ND) outp[(size_t)row * ND + t] = ol[t];
    }
}

extern "C" void kernel_launch(void* const* d_in, const int* in_sizes, int n_in,
                              void* d_out, int out_size, void* d_ws, size_t ws_size,
                              hipStream_t stream)
{
    const float* Q    = (const float*)d_in[0];
    const float* K    = (const float*)d_in[1];
    const float* V    = (const float*)d_in[2];
    const int*   mask = (const int*)d_in[3];
    float* outp = (float*)d_out;
    float* p    = outp + (size_t)NBH * NS * ND;   // p_attn after out

    bool usePack = ws_size >= PM_BYTES + 8 * 1024;
    unsigned char* pm = (unsigned char*)d_ws;
    int* wsl; size_t listBytes;
    if (usePack) { wsl = (int*)((char*)d_ws + PM_BYTES); listBytes = ws_size - PM_BYTES; }
    else         { wsl = (int*)d_ws;                     listBytes = ws_size; }
    int wscap = (listBytes >= 8) ? (int)(listBytes / 4 - 1) : 0;
    if (wscap > 65536) wscap = 65536;

    if (wscap > 0) hipMemsetAsync(wsl, 0, 4, stream);   // reset non-clean count
    if (usePack) pack_mask_kernel<<<NB * NS, 256, 0, stream>>>(mask, pm);

    dim3 grid(NS / TQ, NBH);  // (16, 32)
    if (usePack)
        qk_argmax_kernel<true><<<grid, 256, 0, stream>>>(Q, K, V, mask, pm,
                                                         outp, p, wsl, wscap);
    else
        qk_argmax_kernel<false><<<grid, 256, 0, stream>>>(Q, K, V, mask, nullptr,
                                                          outp, p, wsl, wscap);
    if (wscap > 0)
        slow_rows_kernel<<<dim3(128), 256, 0, stream>>>(Q, K, V, mask, outp, p, wsl, wscap);
}

// Round 3
// 277.249 us; speedup vs baseline: 54.2715x; 54.2715x over previous
//
#include <hip/hip_runtime.h>

// Problem: B=4, H=8, S=2048, D=64
// out  = [B*H*S*D]  floats   (first 4,194,304 of d_out)
// p    = [B*H*S*S]  floats   (next 134,217,728 of d_out)
#define NB 4
#define NH 8
#define NS 2048
#define ND 64
#define NBH (NB * NH)

typedef float f32x4 __attribute__((ext_vector_type(4)));

constexpr int TQ = 128;   // q rows per block
constexpr int TK = 128;   // k cols per tile
constexpr int NT = NS / TK;
constexpr size_t PM_BYTES = (size_t)NB * NS * (NS / 8);   // 2 MiB packed mask

// k-loop barrier: LDS-ordering only. Deliberately does NOT drain vmcnt, so
// p zero-fill stores and prefetch loads float freely across tiles.
__device__ __forceinline__ void barrier_lds() {
    __builtin_amdgcn_sched_barrier(0);
    asm volatile("s_waitcnt lgkmcnt(0)" ::: "memory");
    __builtin_amdgcn_s_barrier();
    __builtin_amdgcn_sched_barrier(0);
}

// ---------------------------------------------------------------------------
// Pack mask int32 -> 1 bit/key. pm[(b*NS + q)*256 + g] bit i = mask[b][q][g*8+i].
// ---------------------------------------------------------------------------
__global__ __launch_bounds__(256)
void pack_mask_kernel(const int* __restrict__ mask, unsigned char* __restrict__ pm)
{
    int idx = blockIdx.x * 256 + threadIdx.x;          // (b*NS + q)*256 + g
    const int* mp = mask + (size_t)idx * 8;
    int4 a = *(const int4*)mp;
    int4 b = *(const int4*)(mp + 4);
    unsigned int v = (a.x != 0)        | ((a.y != 0) << 1)
                   | ((a.z != 0) << 2) | ((a.w != 0) << 3)
                   | ((b.x != 0) << 4) | ((b.y != 0) << 5)
                   | ((b.z != 0) << 6) | ((b.w != 0) << 7);
    pm[idx] = (unsigned char)v;
}

// ---------------------------------------------------------------------------
// Kernel 1: fp32 QK^T with per-row masked top-2 logit tracking.
// Accumulation + top-2 logic bit-identical to round 1. Clean test restored to
// round 1's SCORE-space gap (round 2's logit-space test sent ALL rows to the
// slow path). Structural improvements kept: LDS-only k-loop barriers, K-tile
// register prefetch, packed-mask prefetch, nontemporal zero-fill.
// ---------------------------------------------------------------------------
template<bool PACKED>
__global__ __launch_bounds__(256, 2)
void qk_argmax_kernel(const float* __restrict__ Q,
                      const float* __restrict__ K,
                      const float* __restrict__ V,
                      const int*   __restrict__ mask,
                      const unsigned char* __restrict__ pm,
                      float* __restrict__ outp,
                      float* __restrict__ p,
                      int* __restrict__ wsl, int wscap)
{
    __shared__ float qs[TQ * ND];   // f4 idx = row*16 + (c4 ^ (row>>3))
    __shared__ float ks[TK * ND];
    __shared__ int   argb[TQ];

    const int t  = threadIdx.x;
    const int tx = t & 15;          // key group (8 keys each)
    const int ty = t >> 4;          // row group (8 rows each), 0..15
    const int bh = blockIdx.y;      // 0..31
    const int b  = bh >> 3;
    const int q0 = blockIdx.x * TQ;

    const float* Qb = Q + ((size_t)bh * NS + q0) * ND;
    const float* Kb = K + (size_t)bh * NS * ND;
    const float* Vb = V + (size_t)bh * NS * ND;
    const int*   mb = mask + (size_t)b * NS * NS + (size_t)q0 * NS;
    const unsigned char* pmb = PACKED ? pm + ((size_t)b * NS + q0) * 256 : nullptr;
    float*       pb = p + ((size_t)bh * NS + q0) * NS;

    f32x4* qs4 = (f32x4*)qs;
    f32x4* ks4 = (f32x4*)ks;

    f32x4 kpref[8];                 // next K tile (register prefetch)
    unsigned char mpre[8];          // packed mask bytes, one per row (PACKED)
    int4 m0[8], m1[8];              // fallback mask prefetch (!PACKED)

    auto prefetch_masks = [&](int kt_) {
        if constexpr (PACKED) {
            const unsigned char* pr = pmb + kt_ * 16 + tx;
            #pragma unroll
            for (int j = 0; j < 8; ++j) mpre[j] = pr[(size_t)(ty * 8 + j) * 256];
        } else {
            const int* mrow = mb + kt_ * TK + tx * 8;
            #pragma unroll
            for (int j = 0; j < 8; ++j) {
                m0[j] = *(const int4*)(mrow + (size_t)(ty * 8 + j) * NS);
                m1[j] = *(const int4*)(mrow + (size_t)(ty * 8 + j) * NS + 4);
            }
        }
    };
    auto load_kpref = [&](int kt_) {
        #pragma unroll
        for (int s = 0; s < 8; ++s) {
            int f = t + 256 * s; int row = f >> 4, c4 = f & 15;
            kpref[s] = *(const f32x4*)(Kb + (size_t)(kt_ * TK + row) * ND + c4 * 4);
        }
    };
    auto write_ks = [&]() {
        #pragma unroll
        for (int s = 0; s < 8; ++s) {
            int f = t + 256 * s; int row = f >> 4, c4 = f & 15;
            ks4[row * 16 + (c4 ^ (row >> 3))] = kpref[s];
        }
    };

    // ---- prologue: stage Q + K tile 0, prefetch K tile 1 + masks(0) ----
    {
        f32x4 qpre[8], kpre0[8];
        #pragma unroll
        for (int s = 0; s < 8; ++s) {
            int f = t + 256 * s; int row = f >> 4, c4 = f & 15;
            qpre[s] = *(const f32x4*)(Qb + row * ND + c4 * 4);
        }
        #pragma unroll
        for (int s = 0; s < 8; ++s) {
            int f = t + 256 * s; int row = f >> 4, c4 = f & 15;
            kpre0[s] = *(const f32x4*)(Kb + (size_t)row * ND + c4 * 4);
        }
        load_kpref(1);
        prefetch_masks(0);
        #pragma unroll
        for (int s = 0; s < 8; ++s) {
            int f = t + 256 * s; int row = f >> 4, c4 = f & 15;
            qs4[row * 16 + (c4 ^ (row >> 3))] = qpre[s];
            ks4[row * 16 + (c4 ^ (row >> 3))] = kpre0[s];
        }
    }
    barrier_lds();

    float rm1[8], rm2[8];
    int   ri1[8];
    #pragma unroll
    for (int j = 0; j < 8; ++j) { rm1[j] = -1e30f; rm2[j] = -1e30f; ri1[j] = 0; }

    for (int kt = 0; kt < NT; ++kt) {
        // ---- compute 128x128 logit tile (identical numerics to round 1) ----
        float acc[8][8];
        #pragma unroll
        for (int j = 0; j < 8; ++j)
            #pragma unroll
            for (int i = 0; i < 8; ++i) acc[j][i] = 0.f;

        #pragma unroll 2
        for (int dd = 0; dd < 16; ++dd) {
            f32x4 qv[8], kv[8];
            #pragma unroll
            for (int j = 0; j < 8; ++j) qv[j] = qs4[(ty * 8 + j) * 16 + (dd ^ ty)];
            #pragma unroll
            for (int i = 0; i < 8; ++i) kv[i] = ks4[(tx * 8 + i) * 16 + (dd ^ tx)];
            #pragma unroll
            for (int j = 0; j < 8; ++j)
                #pragma unroll
                for (int i = 0; i < 8; ++i) {
                    acc[j][i] += qv[j].x * kv[i].x;
                    acc[j][i] += qv[j].y * kv[i].y;
                    acc[j][i] += qv[j].z * kv[i].z;
                    acc[j][i] += qv[j].w * kv[i].w;
                }
        }

        // ---- epilogue: mask, top-2, nontemporal zero-fill ----
        float* pz = pb + (size_t)(ty * 8) * NS + kt * TK + tx * 4;
        #pragma unroll
        for (int j = 0; j < 8; ++j) {
            float l[8];
            if constexpr (PACKED) {
                unsigned int mb_ = mpre[j];
                #pragma unroll
                for (int i = 0; i < 8; ++i)
                    l[i] = (mb_ & (1u << i)) ? acc[j][i] : -1e30f;
            } else {
                l[0] = m0[j].x ? acc[j][0] : -1e30f;
                l[1] = m0[j].y ? acc[j][1] : -1e30f;
                l[2] = m0[j].z ? acc[j][2] : -1e30f;
                l[3] = m0[j].w ? acc[j][3] : -1e30f;
                l[4] = m1[j].x ? acc[j][4] : -1e30f;
                l[5] = m1[j].y ? acc[j][5] : -1e30f;
                l[6] = m1[j].z ? acc[j][6] : -1e30f;
                l[7] = m1[j].w ? acc[j][7] : -1e30f;
            }

            float a1 = l[0]; int ai = 0; float a2 = -1e30f;
            #pragma unroll
            for (int i = 1; i < 8; ++i) {
                if (l[i] > a1) { a2 = a1; a1 = l[i]; ai = i; }
                else           { a2 = fmaxf(a2, l[i]); }
            }
            int gkey = kt * TK + tx * 8 + ai;
            if (a1 > rm1[j]) { rm2[j] = fmaxf(rm1[j], a2); rm1[j] = a1; ri1[j] = gkey; }
            else             { rm2[j] = fmaxf(rm2[j], fmaxf(a1, -1e30f)); }

            f32x4 z = {0.f, 0.f, 0.f, 0.f};
            __builtin_nontemporal_store(z, (f32x4*)(pz + (size_t)j * NS));
            __builtin_nontemporal_store(z, (f32x4*)(pz + (size_t)j * NS + 64));
        }

        // ---- stage next K tile; barriers order LDS only (stores float) ----
        if (kt < NT - 1) {
            barrier_lds();                 // all waves done reading ks[kt]
            write_ks();                    // kpref(kt+1) -> LDS
            prefetch_masks(kt + 1);
            if (kt + 2 < NT) load_kpref(kt + 2);
            barrier_lds();                 // ks[kt+1] visible
        }
    }

    // ---- reduce top-2 across the 16 tx lanes (unchanged from round 1) ----
    #pragma unroll
    for (int j = 0; j < 8; ++j) {
        float m1 = rm1[j], m2 = rm2[j];
        int   i1 = ri1[j];
        #pragma unroll
        for (int d = 1; d < 16; d <<= 1) {
            float om1 = __shfl_xor(m1, d, 64);
            float om2 = __shfl_xor(m2, d, 64);
            int   oi1 = __shfl_xor(i1, d, 64);
            float nm1; int ni1; float nm2;
            if (om1 > m1)      { nm1 = om1; ni1 = oi1; nm2 = fmaxf(om2, m1); }
            else if (om1 < m1) { nm1 = m1;  ni1 = i1;  nm2 = fmaxf(m2, om1); }
            else {
                nm1 = m1; ni1 = i1;
                nm2 = (oi1 == i1) ? fmaxf(m2, om2) : m1; // distinct-key tie -> gap 0
            }
            m1 = nm1; i1 = ni1; m2 = nm2;
        }
        if (tx == 0) {
            int qrow = ty * 8 + j;
            // SCORE-space gap test (round 1 semantics — softmax sees exp(l)/8):
            // residual softmax mass <= 2047*e^-15 ~ 6e-4 << 0.0975 threshold.
            float s1 = __expf(m1) * 0.125f;
            float s2 = __expf(m2) * 0.125f;
            bool clean = (m1 > -1e29f) && (s1 < 1e38f) && (s1 - s2 > 15.0f);
            if (clean) argb[qrow] = i1;
            else if (wscap > 0) {
                argb[qrow] = -1;
                int idx = atomicAdd(wsl, 1);
                if (idx < wscap) wsl[1 + idx] = bh * NS + q0 + qrow;
            } else {
                argb[qrow] = i1;   // no workspace: best-effort fallback
            }
        }
    }
    __syncthreads();   // FULL drain (vmcnt(0)): zero stores complete before 1.0

    // ---- emit one-hot + out = V[argmax] for clean rows ----
    #pragma unroll
    for (int s = 0; s < 8; ++s) {
        int task = t + 256 * s;          // 2048 tasks = 128 rows x 16 float4s
        int row = task >> 4, c4 = task & 15;
        int a = argb[row];
        if (a >= 0) {
            *(float4*)(outp + ((size_t)bh * NS + q0 + row) * ND + c4 * 4) =
                *(const float4*)(Vb + (size_t)a * ND + c4 * 4);
            if (c4 == 0) pb[(size_t)row * NS + a] = 1.0f;
        }
    }
}

// ---------------------------------------------------------------------------
// Kernel 2: exact reference softmax for listed (non-one-hot) rows (unchanged).
// ---------------------------------------------------------------------------
__global__ __launch_bounds__(256)
void slow_rows_kernel(const float* __restrict__ Q, const float* __restrict__ K,
                      const float* __restrict__ V, const int* __restrict__ mask,
                      float* __restrict__ outp, float* __restrict__ p,
                      const int* __restrict__ wsl, int wscap)
{
    __shared__ float qr[ND];
    __shared__ float redm[4], redz[4];
    __shared__ float ol[ND];
    int n = wsl[0];
    if (n > wscap) n = wscap;
    const int t = threadIdx.x;
    const int lane = t & 63, w = t >> 6;

    for (int ii = blockIdx.x; ii < n; ii += gridDim.x) {
        int row = wsl[1 + ii];           // global row = bh*NS + q
        int bh = row >> 11, q = row & (NS - 1), b = bh >> 3;
        const float* Qr = Q + (size_t)row * ND;
        const float* Kb = K + (size_t)bh * NS * ND;
        const float* Vb = V + (size_t)bh * NS * ND;
        const int*   mr = mask + (size_t)b * NS * NS + (size_t)q * NS;

        __syncthreads();
        if (t < 16) ((float4*)qr)[t] = ((const float4*)Qr)[t];
        if (t < ND) ol[t] = 0.f;
        __syncthreads();

        float sc[8];
        int k0 = t * 8;
        #pragma unroll
        for (int i = 0; i < 8; ++i) {
            const float* kr = Kb + (size_t)(k0 + i) * ND;
            float a = 0.f;
            for (int d = 0; d < ND; d += 4) {
                float4 kv = *(const float4*)(kr + d);
                a += qr[d] * kv.x; a += qr[d + 1] * kv.y;
                a += qr[d + 2] * kv.z; a += qr[d + 3] * kv.w;
            }
            sc[i] = mr[k0 + i] ? __expf(a) * 0.125f : -1e9f;
        }
        float m = sc[0];
        #pragma unroll
        for (int i = 1; i < 8; ++i) m = fmaxf(m, sc[i]);
        #pragma unroll
        for (int d = 1; d < 64; d <<= 1) m = fmaxf(m, __shfl_xor(m, d, 64));
        if (lane == 0) redm[w] = m;
        __syncthreads();
        m = fmaxf(fmaxf(redm[0], redm[1]), fmaxf(redm[2], redm[3]));

        float e[8]; float z = 0.f;
        #pragma unroll
        for (int i = 0; i < 8; ++i) { e[i] = __expf(sc[i] - m); z += e[i]; }
        #pragma unroll
        for (int d = 1; d < 64; d <<= 1) z += __shfl_xor(z, d, 64);
        if (lane == 0) redz[w] = z;
        __syncthreads();
        float Z = redz[0] + redz[1] + redz[2] + redz[3];
        float inv = 1.f / Z;

        float* pr = p + (size_t)row * NS + k0;
        float4 o0, o1;
        o0.x = e[0] * inv; o0.y = e[1] * inv; o0.z = e[2] * inv; o0.w = e[3] * inv;
        o1.x = e[4] * inv; o1.y = e[5] * inv; o1.z = e[6] * inv; o1.w = e[7] * inv;
        *(float4*)pr = o0; *(float4*)(pr + 4) = o1;

        #pragma unroll
        for (int i = 0; i < 8; ++i) {
            float pv = e[i] * inv;
            if (pv > 0.f) {
                const float* vr = Vb + (size_t)(k0 + i) * ND;
                for (int d = 0; d < ND; ++d) atomicAdd(&ol[d], pv * vr[d]);
            }
        }
        __syncthreads();
        if (t < ND) outp[(size_t)row * ND + t] = ol[t];
    }
}

extern "C" void kernel_launch(void* const* d_in, const int* in_sizes, int n_in,
                              void* d_out, int out_size, void* d_ws, size_t ws_size,
                              hipStream_t stream)
{
    const float* Q    = (const float*)d_in[0];
    const float* K    = (const float*)d_in[1];
    const float* V    = (const float*)d_in[2];
    const int*   mask = (const int*)d_in[3];
    float* outp = (float*)d_out;
    float* p    = outp + (size_t)NBH * NS * ND;   // p_attn after out

    bool usePack = ws_size >= PM_BYTES + 8 * 1024;
    unsigned char* pm = (unsigned char*)d_ws;
    int* wsl; size_t listBytes;
    if (usePack) { wsl = (int*)((char*)d_ws + PM_BYTES); listBytes = ws_size - PM_BYTES; }
    else         { wsl = (int*)d_ws;                     listBytes = ws_size; }
    int wscap = (listBytes >= 8) ? (int)(listBytes / 4 - 1) : 0;
    if (wscap > 65536) wscap = 65536;

    if (wscap > 0) hipMemsetAsync(wsl, 0, 4, stream);   // reset non-clean count
    if (usePack) pack_mask_kernel<<<NB * NS, 256, 0, stream>>>(mask, pm);

    dim3 grid(NS / TQ, NBH);  // (16, 32)
    if (usePack)
        qk_argmax_kernel<true><<<grid, 256, 0, stream>>>(Q, K, V, mask, pm,
                                                         outp, p, wsl, wscap);
    else
        qk_argmax_kernel<false><<<grid, 256, 0, stream>>>(Q, K, V, mask, nullptr,
                                                          outp, p, wsl, wscap);
    if (wscap > 0)
        slow_rows_kernel<<<dim3(128), 256, 0, stream>>>(Q, K, V, mask, outp, p, wsl, wscap);
}

// Round 4
// 202.815 us; speedup vs baseline: 74.1895x; 1.3670x over previous
//
#include <hip/hip_runtime.h>

// Problem: B=4, H=8, S=2048, D=64
// out  = [B*H*S*D]  floats   (first 4,194,304 of d_out)
// p    = [B*H*S*S]  floats   (next 134,217,728 of d_out)
#define NB 4
#define NH 8
#define NS 2048
#define ND 64
#define NBH (NB * NH)

typedef float f32x4  __attribute__((ext_vector_type(4)));
typedef float f32x16 __attribute__((ext_vector_type(16)));
typedef short s16x8  __attribute__((ext_vector_type(8)));
typedef unsigned int u32;

constexpr int TQ = 128;   // q rows per block
constexpr int TK = 128;   // keys per tile
constexpr int NT = NS / TK;
constexpr size_t PM_BYTES = (size_t)NB * NS * (NS / 8);   // 2 MiB packed mask

// LDS-ordering-only barrier (does not drain vmcnt: stores/prefetch float free)
__device__ __forceinline__ void barrier_lds() {
    __builtin_amdgcn_sched_barrier(0);
    asm volatile("s_waitcnt lgkmcnt(0)" ::: "memory");
    __builtin_amdgcn_s_barrier();
    __builtin_amdgcn_sched_barrier(0);
}

// f32 -> bf16 RNE bits
__device__ __forceinline__ u32 bf16_rne(u32 u) {
    return (u + 0x7FFFu + ((u >> 16) & 1u)) >> 16;
}
// split x = hi + lo (both bf16-representable), RNE both
__device__ __forceinline__ void cvt_split(float x, u32 &hi, u32 &lo) {
    u32 h = bf16_rne(__float_as_uint(x));
    float hf = __uint_as_float(h << 16);
    lo = bf16_rne(__float_as_uint(x - hf));
    hi = h;
}

// ---------------------------------------------------------------------------
// Pack mask int32 -> 1 bit/key. Bit (key%32) of word [(b*NS+q)*64 + key/32].
// ---------------------------------------------------------------------------
__global__ __launch_bounds__(256)
void pack_mask_kernel(const int* __restrict__ mask, unsigned char* __restrict__ pm)
{
    int idx = blockIdx.x * 256 + threadIdx.x;          // (b*NS + q)*256 + g
    const int* mp = mask + (size_t)idx * 8;
    int4 a = *(const int4*)mp;
    int4 b = *(const int4*)(mp + 4);
    unsigned int v = (a.x != 0)        | ((a.y != 0) << 1)
                   | ((a.z != 0) << 2) | ((a.w != 0) << 3)
                   | ((b.x != 0) << 4) | ((b.y != 0) << 5)
                   | ((b.z != 0) << 6) | ((b.w != 0) << 7);
    pm[idx] = (unsigned char)v;
}

// ---------------------------------------------------------------------------
// Kernel 1: bf16-split MFMA QK^T (swapped: C[key,q] = K x Q^T) with per-lane
// masked top-2 logit tracking. Lane owns q-row (lane&31); keys split across
// lane halves; final merge = one shfl_xor(32). 3-term split error ~5e-5 is
// guarded by the (m1-m2 > 1e-3) gap test -> ambiguous rows go to slow path.
// ---------------------------------------------------------------------------
__global__ __launch_bounds__(256, 2)
void qk_mfma_kernel(const float* __restrict__ Q,
                    const float* __restrict__ K,
                    const float* __restrict__ V,
                    const unsigned char* __restrict__ pm,
                    float* __restrict__ outp,
                    float* __restrict__ p,
                    int* __restrict__ wsl, int wscap)
{
    // K tile as bf16 planes: [buf][cp = chunk*2+plane][key*8 + half*4], chunk=d/8.
    // Row stride 1032 shorts (=2064 B, non-pow2 pad) kills bank aliasing.
    __shared__ __align__(16) short kbuf[2][16][1032];
    __shared__ int argb[TQ];

    const int t  = threadIdx.x;
    const int l  = t & 63;
    const int wv = t >> 6;          // wave 0..3 -> q sub-tile
    const int hl = l >> 5;          // lane half (selects d-half and key subset)
    const int ln = l & 31;
    const int bh = blockIdx.x;      // head index (XCD-local K/V reuse)
    const int b  = bh >> 3;
    const int q0 = blockIdx.y * TQ;

    const float* Kb = K + (size_t)bh * NS * ND;
    const float* Vb = V + (size_t)bh * NS * ND;
    float*       pb = p + ((size_t)bh * NS + q0) * NS;
    const u32*  pm32 = (const u32*)pm;

    const int q = q0 + wv * 32 + ln;       // this lane's q-row

    // ---- Q fragments in registers (hi/lo planes, 4 dsteps of K=16) ----
    s16x8 qh[4], ql[4];
    {
        const float* Qr = Q + ((size_t)bh * NS + q) * ND + hl * 8;
        #pragma unroll
        for (int d_ = 0; d_ < 4; ++d_) {
            f32x4 v0 = *(const f32x4*)(Qr + d_ * 16);
            f32x4 v1 = *(const f32x4*)(Qr + d_ * 16 + 4);
            u32 h[8], lo[8];
            cvt_split(v0.x, h[0], lo[0]); cvt_split(v0.y, h[1], lo[1]);
            cvt_split(v0.z, h[2], lo[2]); cvt_split(v0.w, h[3], lo[3]);
            cvt_split(v1.x, h[4], lo[4]); cvt_split(v1.y, h[5], lo[5]);
            cvt_split(v1.z, h[6], lo[6]); cvt_split(v1.w, h[7], lo[7]);
            union { u32 u[4]; s16x8 s; } H, L;
            #pragma unroll
            for (int e = 0; e < 4; ++e) {
                H.u[e] = h[2*e]  | (h[2*e+1]  << 16);
                L.u[e] = lo[2*e] | (lo[2*e+1] << 16);
            }
            qh[d_] = H.s; ql[d_] = L.s;
        }
    }

    f32x4 kpref[8];                 // next K tile (f32 register prefetch)
    auto load_kpref = [&](int kt_) {
        #pragma unroll
        for (int s = 0; s < 8; ++s) {
            int f = t + 256 * s; int key = f >> 4, c4 = f & 15;
            kpref[s] = *(const f32x4*)(Kb + (size_t)(kt_ * TK + key) * ND + c4 * 4);
        }
    };
    auto write_ks = [&](int bufsel) {
        #pragma unroll
        for (int s = 0; s < 8; ++s) {
            int f = t + 256 * s; int key = f >> 4, c4 = f & 15;
            int chunk = c4 >> 1, half = c4 & 1;
            f32x4 v = kpref[s];
            u32 h0,l0,h1,l1,h2,l2,h3,l3;
            cvt_split(v.x,h0,l0); cvt_split(v.y,h1,l1);
            cvt_split(v.z,h2,l2); cvt_split(v.w,h3,l3);
            uint2 H = make_uint2(h0 | (h1<<16), h2 | (h3<<16));
            uint2 L = make_uint2(l0 | (l1<<16), l2 | (l3<<16));
            *(uint2*)&kbuf[bufsel][chunk*2    ][key*8 + half*4] = H;
            *(uint2*)&kbuf[bufsel][chunk*2 + 1][key*8 + half*4] = L;
        }
    };

    // ---- prologue: stage tile 0, prefetch tile 1 ----
    load_kpref(0);
    write_ks(0);
    load_kpref(1);
    barrier_lds();

    float m1 = -1e30f, m2 = -1e30f;
    int   i1 = 0;
    int   c  = 0;

    for (int kt = 0; kt < NT; ++kt) {
        // mask words for this tile (L2/L3-hot), pre-shifted for lane half
        u32 mwv[4];
        #pragma unroll
        for (int ks = 0; ks < 4; ++ks)
            mwv[ks] = pm32[((size_t)b * NS + q) * 64 + kt * 4 + ks] >> (hl * 4);

        auto top2 = [&](const f32x16& A, int ks) {
            u32 ws = mwv[ks];
            int kbase = kt * 128 + ks * 32 + hl * 4;
            #pragma unroll
            for (int r = 0; r < 16; ++r) {
                int bp = (r & 3) + 8 * (r >> 2);        // C-row pattern (m74/m101)
                float v = ((ws >> bp) & 1u) ? A[r] : -1e30f;
                bool gt = v > m1;
                m2 = gt ? m1 : fmaxf(m2, v);
                m1 = fmaxf(m1, v);
                i1 = gt ? (kbase + bp) : i1;
            }
        };

        #pragma unroll
        for (int kp = 0; kp < 2; ++kp) {                // key sub-tile pairs
            f32x16 acc0 = {0.f}; f32x16 acc1 = {0.f};
            #pragma unroll
            for (int r = 0; r < 16; ++r) { acc0[r] = 0.f; acc1[r] = 0.f; }
            #pragma unroll
            for (int d_ = 0; d_ < 4; ++d_) {            // K=16 steps over D=64
                int cpA = d_ * 4 + hl * 2;
                s16x8 ah0 = *(const s16x8*)&kbuf[c][cpA    ][(kp*64      + ln) * 8];
                s16x8 al0 = *(const s16x8*)&kbuf[c][cpA + 1][(kp*64      + ln) * 8];
                s16x8 ah1 = *(const s16x8*)&kbuf[c][cpA    ][(kp*64 + 32 + ln) * 8];
                s16x8 al1 = *(const s16x8*)&kbuf[c][cpA + 1][(kp*64 + 32 + ln) * 8];
                // 3-term split: Kh*Qh + Kl*Qh + Kh*Ql
                acc0 = __builtin_amdgcn_mfma_f32_32x32x16_bf16(ah0, qh[d_], acc0, 0,0,0);
                acc1 = __builtin_amdgcn_mfma_f32_32x32x16_bf16(ah1, qh[d_], acc1, 0,0,0);
                acc0 = __builtin_amdgcn_mfma_f32_32x32x16_bf16(al0, qh[d_], acc0, 0,0,0);
                acc1 = __builtin_amdgcn_mfma_f32_32x32x16_bf16(al1, qh[d_], acc1, 0,0,0);
                acc0 = __builtin_amdgcn_mfma_f32_32x32x16_bf16(ah0, ql[d_], acc0, 0,0,0);
                acc1 = __builtin_amdgcn_mfma_f32_32x32x16_bf16(ah1, ql[d_], acc1, 0,0,0);
            }
            top2(acc0, kp * 2);
            top2(acc1, kp * 2 + 1);
        }

        // ---- zero-fill this 128x128 p tile (nontemporal, never waited) ----
        {
            const int tx = t & 15, ty = t >> 4;
            float* pz = pb + (size_t)(ty * 8) * NS + kt * TK + tx * 4;
            #pragma unroll
            for (int j = 0; j < 8; ++j) {
                f32x4 z = {0.f, 0.f, 0.f, 0.f};
                __builtin_nontemporal_store(z, (f32x4*)(pz + (size_t)j * NS));
                __builtin_nontemporal_store(z, (f32x4*)(pz + (size_t)j * NS + 64));
            }
        }

        // ---- stage next tile into the other buffer; ONE barrier per tile ----
        if (kt < NT - 1) {
            write_ks(c ^ 1);                  // safe: buf c^1 last read pre-barrier(kt-1)
            if (kt + 2 < NT) load_kpref(kt + 2);
            barrier_lds();
            c ^= 1;
        }
    }

    // ---- merge lane halves (disjoint key sets) ----
    {
        float om1 = __shfl_xor(m1, 32, 64);
        float om2 = __shfl_xor(m2, 32, 64);
        int   oi1 = __shfl_xor(i1, 32, 64);
        float nm1, nm2; int ni1;
        if (om1 > m1)      { nm1 = om1; ni1 = oi1; nm2 = fmaxf(om2, m1); }
        else if (om1 < m1) { nm1 = m1;  ni1 = i1;  nm2 = fmaxf(m2, om1); }
        else { nm1 = m1; ni1 = i1; nm2 = (oi1 == i1) ? fmaxf(m2, om2) : m1; }
        m1 = nm1; i1 = ni1; m2 = nm2;
    }

    if (l < 32) {
        int qrow = wv * 32 + ln;
        // score-space one-hot test + logit-gap guard for bf16-split error
        float s1 = __expf(m1) * 0.125f;
        float s2 = __expf(m2) * 0.125f;
        bool clean = (m1 > -1e29f) && (s1 < 1e38f) && (s1 - s2 > 15.0f)
                     && (m1 - m2 > 1e-3f);
        if (clean) argb[qrow] = i1;
        else if (wscap > 0) {
            argb[qrow] = -1;
            int idx = atomicAdd(wsl, 1);
            if (idx < wscap) wsl[1 + idx] = bh * NS + q0 + qrow;
        } else {
            argb[qrow] = i1;   // no workspace: best-effort fallback
        }
    }
    __syncthreads();   // FULL drain (vmcnt(0)): zero stores complete before 1.0

    // ---- emit one-hot + out = V[argmax] for clean rows ----
    #pragma unroll
    for (int s = 0; s < 8; ++s) {
        int task = t + 256 * s;          // 2048 tasks = 128 rows x 16 float4s
        int row = task >> 4, c4 = task & 15;
        int a = argb[row];
        if (a >= 0) {
            *(float4*)(outp + ((size_t)bh * NS + q0 + row) * ND + c4 * 4) =
                *(const float4*)(Vb + (size_t)a * ND + c4 * 4);
            if (c4 == 0) pb[(size_t)row * NS + a] = 1.0f;
        }
    }
}

// ---------------------------------------------------------------------------
// Kernel 2: exact reference softmax for listed rows (or ALL rows if allrows).
// ---------------------------------------------------------------------------
__global__ __launch_bounds__(256)
void slow_rows_kernel(const float* __restrict__ Q, const float* __restrict__ K,
                      const float* __restrict__ V, const int* __restrict__ mask,
                      float* __restrict__ outp, float* __restrict__ p,
                      const int* __restrict__ wsl, int wscap, int allrows)
{
    __shared__ float qr[ND];
    __shared__ float redm[4], redz[4];
    __shared__ float ol[ND];
    int n;
    if (allrows) n = NBH * NS;
    else { n = wsl[0]; if (n > wscap) n = wscap; }
    const int t = threadIdx.x;
    const int lane = t & 63, w = t >> 6;

    for (int ii = blockIdx.x; ii < n; ii += gridDim.x) {
        int row = allrows ? ii : wsl[1 + ii];   // global row = bh*NS + q
        int bh = row >> 11, qq = row & (NS - 1), b = bh >> 3;
        const float* Qr = Q + (size_t)row * ND;
        const float* Kb = K + (size_t)bh * NS * ND;
        const float* Vb = V + (size_t)bh * NS * ND;
        const int*   mr = mask + (size_t)b * NS * NS + (size_t)qq * NS;

        __syncthreads();
        if (t < 16) ((float4*)qr)[t] = ((const float4*)Qr)[t];
        if (t < ND) ol[t] = 0.f;
        __syncthreads();

        float sc[8];
        int k0 = t * 8;
        #pragma unroll
        for (int i = 0; i < 8; ++i) {
            const float* kr = Kb + (size_t)(k0 + i) * ND;
            float a = 0.f;
            for (int d = 0; d < ND; d += 4) {
                float4 kv = *(const float4*)(kr + d);
                a += qr[d] * kv.x; a += qr[d + 1] * kv.y;
                a += qr[d + 2] * kv.z; a += qr[d + 3] * kv.w;
            }
            sc[i] = mr[k0 + i] ? __expf(a) * 0.125f : -1e9f;
        }
        float m = sc[0];
        #pragma unroll
        for (int i = 1; i < 8; ++i) m = fmaxf(m, sc[i]);
        #pragma unroll
        for (int d = 1; d < 64; d <<= 1) m = fmaxf(m, __shfl_xor(m, d, 64));
        if (lane == 0) redm[w] = m;
        __syncthreads();
        m = fmaxf(fmaxf(redm[0], redm[1]), fmaxf(redm[2], redm[3]));

        float e[8]; float z = 0.f;
        #pragma unroll
        for (int i = 0; i < 8; ++i) { e[i] = __expf(sc[i] - m); z += e[i]; }
        #pragma unroll
        for (int d = 1; d < 64; d <<= 1) z += __shfl_xor(z, d, 64);
        if (lane == 0) redz[w] = z;
        __syncthreads();
        float Z = redz[0] + redz[1] + redz[2] + redz[3];
        float inv = 1.f / Z;

        float* pr = p + (size_t)row * NS + k0;
        float4 o0, o1;
        o0.x = e[0] * inv; o0.y = e[1] * inv; o0.z = e[2] * inv; o0.w = e[3] * inv;
        o1.x = e[4] * inv; o1.y = e[5] * inv; o1.z = e[6] * inv; o1.w = e[7] * inv;
        *(float4*)pr = o0; *(float4*)(pr + 4) = o1;

        #pragma unroll
        for (int i = 0; i < 8; ++i) {
            float pv = e[i] * inv;
            if (pv > 0.f) {
                const float* vr = Vb + (size_t)(k0 + i) * ND;
                for (int d = 0; d < ND; ++d) atomicAdd(&ol[d], pv * vr[d]);
            }
        }
        __syncthreads();
        if (t < ND) outp[(size_t)row * ND + t] = ol[t];
    }
}

extern "C" void kernel_launch(void* const* d_in, const int* in_sizes, int n_in,
                              void* d_out, int out_size, void* d_ws, size_t ws_size,
                              hipStream_t stream)
{
    const float* Q    = (const float*)d_in[0];
    const float* K    = (const float*)d_in[1];
    const float* V    = (const float*)d_in[2];
    const int*   mask = (const int*)d_in[3];
    float* outp = (float*)d_out;
    float* p    = outp + (size_t)NBH * NS * ND;   // p_attn after out

    if (ws_size < PM_BYTES + 8 * 1024) {
        // No workspace for packed mask + list: exact path for everything.
        slow_rows_kernel<<<dim3(4096), 256, 0, stream>>>(Q, K, V, mask, outp, p,
                                                         nullptr, 0, 1);
        return;
    }

    unsigned char* pm = (unsigned char*)d_ws;
    int* wsl = (int*)((char*)d_ws + PM_BYTES);
    size_t listBytes = ws_size - PM_BYTES;
    int wscap = (int)(listBytes / 4 - 1);
    if (wscap > 65536) wscap = 65536;

    hipMemsetAsync(wsl, 0, 4, stream);                 // reset non-clean count
    pack_mask_kernel<<<NB * NS, 256, 0, stream>>>(mask, pm);

    dim3 grid(NBH, NS / TQ);   // x = head (same-head blocks -> same XCD), y = q-tile
    qk_mfma_kernel<<<grid, 256, 0, stream>>>(Q, K, V, pm, outp, p, wsl, wscap);

    slow_rows_kernel<<<dim3(128), 256, 0, stream>>>(Q, K, V, mask, outp, p,
                                                    wsl, wscap, 0);
}